// Round 2
// baseline (170.141 us; speedup 1.0000x reference)
//
#include <hip/hip_runtime.h>

// LocalNonLocal2D: fused local-correlation + normalize + local-aggregation.
// N=4, C=128, H=W=80, K=7. fp32 throughout (pathological normalization
// denominators in the fixed input forbid bf16 on phase 1).
//
// Structure: 1-wave (64-thread) blocks, 16x4 pixel tile. Per 4-channel group,
// a 22x10 halo tile is staged into LDS in channel-interleaved float4 layout
// via global_load_lds (per-lane clamped source addresses), double-buffered
// with counted s_waitcnt vmcnt(14) — no barriers needed with a single wave.

namespace {

constexpr int CN = 4;          // batch
constexpr int CC = 128;        // channels
constexpr int HT = 80, WD = 80;
constexpr int KK = 7, K2 = 49, PD = 3;
constexpr int TW = 16, TH = 4;            // pixel tile per block
constexpr int HW_ = TW + 6;               // 22 halo cols
constexpr int HH_ = TH + 6;               // 10 halo rows
constexpr int HENT = HW_ * HH_;           // 220 halo entries (float4 each)
constexpr int HFLT = HENT * 4;            // 880 floats
constexpr int HCHUNK = (HFLT + 63) / 64;  // 14 load chunks of 64 floats
constexpr int HPADF = HCHUNK * 64;        // 896 (padded LDS buffer)
constexpr int PLANE = HT * WD;            // 6400
constexpr int GSTRIDE = 4 * PLANE;        // elements per 4-channel group step
constexpr int OUT_ELEMS = CN * CC * PLANE;   // 3,276,800 (out), then pairwise

__device__ __forceinline__ void issue_chunks(const float* gbase, const int* off,
                                             float* lds, int tid) {
#if __has_builtin(__builtin_amdgcn_global_load_lds)
#pragma unroll
  for (int q = 0; q < HCHUNK; ++q) {
    __builtin_amdgcn_global_load_lds(
        (const __attribute__((address_space(1))) void*)(gbase + off[q]),
        (__attribute__((address_space(3))) void*)(lds + q * 64), 4, 0, 0);
  }
#else
  // synchronous fallback (correct, slower)
#pragma unroll
  for (int q = 0; q < HCHUNK; ++q) lds[q * 64 + tid] = gbase[off[q]];
  asm volatile("s_waitcnt lgkmcnt(0)" ::: "memory");
#endif
}

#define WAIT_VM(n_lit)                                      \
  asm volatile("s_waitcnt vmcnt(" #n_lit ")" ::: "memory"); \
  __builtin_amdgcn_sched_barrier(0)

__global__ __launch_bounds__(64) void lnl2d_fused(const float* __restrict__ x,
                                                  const float* __restrict__ feat,
                                                  float* __restrict__ dout) {
  __shared__ float halo[2][HPADF];
  __shared__ float wstage[TH * TW * K2];  // 3136 floats for coalesced pw store

  const int tid = (int)threadIdx.x;
  const int tx = tid & (TW - 1);
  const int ty = tid >> 4;
  const int bx = (int)blockIdx.x;  // 5 tiles along W
  const int by = (int)blockIdx.y;  // 20 tiles along H
  const int n  = (int)blockIdx.z;

  const int h = by * TH + ty;
  const int w = bx * TW + tx;

  const float* xn = x + (size_t)n * CC * PLANE;
  const float* fn = feat + (size_t)n * CC * PLANE;
  float* out = dout;
  float* pw  = dout + OUT_ELEMS;

  // Per-lane source offsets (elements) for the 14 staging chunks of group 0.
  // Halo coordinates are CLAMPED into the image: OOB entries hold garbage
  // (finite) values; the corresponding w[k] are zeroed post-accumulation.
  int off[HCHUNK];
#pragma unroll
  for (int q = 0; q < HCHUNK; ++q) {
    int f = q * 64 + tid;
    int e = f >> 2;
    if (e > HENT - 1) e = HENT - 1;     // pad lanes re-load last entry
    const int ch = f & 3;
    const int r  = e / HW_;
    const int cl = e - r * HW_;
    int gh = by * TH - PD + r;
    gh = gh < 0 ? 0 : (gh > HT - 1 ? HT - 1 : gh);
    int gw = bx * TW - PD + cl;
    gw = gw < 0 ? 0 : (gw > WD - 1 ? WD - 1 : gw);
    off[q] = ch * PLANE + gh * WD + gw;
  }

  float acc[K2];
#pragma unroll
  for (int k = 0; k < K2; ++k) acc[k] = 0.f;

  // ---------------- phase 1: w[k] = sum_c x_center * x_neighbor -------------
  auto p1_compute = [&](const float* hb) {
    const float4 c4 = *(const float4*)(hb + ((ty + PD) * HW_ + (tx + PD)) * 4);
#pragma unroll
    for (int di = 0; di < KK; ++di) {
#pragma unroll
      for (int dj = 0; dj < KK; ++dj) {
        const float4 n4 = *(const float4*)(hb + ((ty + di) * HW_ + (tx + dj)) * 4);
        acc[di * KK + dj] += c4.x * n4.x + c4.y * n4.y + c4.z * n4.z + c4.w * n4.w;
      }
    }
  };

  issue_chunks(xn, off, halo[0], tid);
  int goff = GSTRIDE;
  for (int g = 0; g < 31; ++g) {
    issue_chunks(xn + goff, off, halo[(g + 1) & 1], tid);
    goff += GSTRIDE;
    WAIT_VM(14);  // current group's 14 loads done; next group's stay in flight
    p1_compute(halo[g & 1]);
  }
  // Prefetch feat group 0 into halo[0]; last x group sits in halo[1].
  issue_chunks(fn, off, halo[0], tid);
  WAIT_VM(14);
  p1_compute(halo[1]);

  // Zero OOB offsets (matches zero-padding), normalize by plain sum.
#pragma unroll
  for (int di = 0; di < KK; ++di) {
#pragma unroll
    for (int dj = 0; dj < KK; ++dj) {
      const int hh = h + di - PD, ww = w + dj - PD;
      if ((unsigned)hh >= (unsigned)HT || (unsigned)ww >= (unsigned)WD)
        acc[di * KK + dj] = 0.f;
    }
  }
  float ssum = 0.f;
#pragma unroll
  for (int k = 0; k < K2; ++k) ssum += acc[k];
  const float invs = 1.0f / ssum;
#pragma unroll
  for (int k = 0; k < K2; ++k) acc[k] *= invs;

  // pairwise_weight store: LDS transpose so global writes are lane-contiguous.
  // wstage bank pattern: tid*49 mod 32 = tid*17 mod 32 -> 2-way (free).
#pragma unroll
  for (int k = 0; k < K2; ++k) wstage[tid * K2 + k] = acc[k];
  __syncthreads();  // single wave: cheap; orders ds_write -> cross-lane ds_read
#pragma unroll
  for (int r = 0; r < TH; ++r) {
    float* dst = pw + (size_t)(n * PLANE + (by * TH + r) * WD + bx * TW) * K2;
    const float* src = wstage + r * TW * K2;
#pragma unroll
    for (int c2 = 0; c2 < (TW * K2) / 64; ++c2)  // 12 full chunks
      dst[c2 * 64 + tid] = src[c2 * 64 + tid];
    if (tid < (TW * K2) - 64 * ((TW * K2) / 64))  // 16 remainder
      dst[64 * ((TW * K2) / 64) + tid] = src[64 * ((TW * K2) / 64) + tid];
  }

  // ---------------- phase 2: out[c] = sum_k w[k] * feat_neighbor ------------
  const size_t obase = (size_t)n * CC * PLANE + (size_t)(h * WD + w);
  auto p2_compute = [&](const float* hb, int g) {
    float4 a = make_float4(0.f, 0.f, 0.f, 0.f);
#pragma unroll
    for (int di = 0; di < KK; ++di) {
#pragma unroll
      for (int dj = 0; dj < KK; ++dj) {
        const float4 n4 = *(const float4*)(hb + ((ty + di) * HW_ + (tx + dj)) * 4);
        const float wk = acc[di * KK + dj];
        a.x += wk * n4.x; a.y += wk * n4.y; a.z += wk * n4.z; a.w += wk * n4.w;
      }
    }
    out[obase + (size_t)(4 * g + 0) * PLANE] = a.x;
    out[obase + (size_t)(4 * g + 1) * PLANE] = a.y;
    out[obase + (size_t)(4 * g + 2) * PLANE] = a.z;
    out[obase + (size_t)(4 * g + 3) * PLANE] = a.w;
  };

  goff = GSTRIDE;
  for (int g = 0; g < 31; ++g) {
    issue_chunks(fn + goff, off, halo[(g + 1) & 1], tid);
    goff += GSTRIDE;
    WAIT_VM(14);
    p2_compute(halo[g & 1], g);
  }
  WAIT_VM(0);
  p2_compute(halo[1], 31);
}

}  // namespace

extern "C" void kernel_launch(void* const* d_in, const int* in_sizes, int n_in,
                              void* d_out, int out_size, void* d_ws, size_t ws_size,
                              hipStream_t stream) {
  const float* x    = (const float*)d_in[0];
  const float* feat = (const float*)d_in[1];
  float* out        = (float*)d_out;
  dim3 grid(WD / TW, HT / TH, CN);  // (5, 20, 4) = 400 blocks, 64 threads each
  lnl2d_fused<<<grid, 64, 0, stream>>>(x, feat, out);
}

// Round 3
// 142.886 us; speedup vs baseline: 1.1907x; 1.1907x over previous
//
#include <hip/hip_runtime.h>

// LocalNonLocal2D fused pipeline, v2: 4-way channel-split across blocks.
//   kernel 1 (corr): per-chunk partial correlation w[49] -> ws (21.3 MB)
//   kernel 2 (agg):  sum partials, normalize, aggregate, write out+pairwise
// 1-wave blocks, 16x4 pixel tile, triple-buffered halo staging via
// global_load_lds with counted s_waitcnt vmcnt(28) (2 groups in flight).
// All global stores kept OUTSIDE counted-vmcnt loops (stores count in vmcnt).
// Falls back to the v1 single fused kernel if ws_size is too small.

namespace {

constexpr int CN = 4, CC = 128, HT = 80, WD = 80;
constexpr int KK = 7, K2 = 49, PD = 3;
constexpr int TW = 16, TH = 4;            // pixel tile (64 px = 1 wave)
constexpr int HW_ = TW + 6;               // 22 halo cols
constexpr int HH_ = TH + 6;               // 10 halo rows
constexpr int HENT = HW_ * HH_;           // 220 float4 halo entries
constexpr int HCHUNK = (HENT * 4 + 63) / 64;  // 14 load chunks of 64 floats
constexpr int HPADF = HCHUNK * 64;        // 896 floats per halo buffer
constexpr int PLANE = HT * WD;            // 6400
constexpr int GSTRIDE = 4 * PLANE;        // one 4-channel group step
constexpr int OUT_ELEMS = CN * CC * PLANE;
constexpr int CHUNKS = 4, GPC = 8;        // 4 chunks x 8 groups x 4ch = 128
constexpr int NTILES = 5 * 20 * CN;       // 400 pixel tiles
constexpr int WPAD = 52;                  // 49 -> 52 floats (16B aligned rows)
constexpr size_t WS_NEED = (size_t)CHUNKS * NTILES * 64 * WPAD * 4;

__device__ __forceinline__ void make_off(int* off, int bx, int by, int tid) {
#pragma unroll
  for (int q = 0; q < HCHUNK; ++q) {
    int f = q * 64 + tid;
    int e = f >> 2;
    if (e > HENT - 1) e = HENT - 1;  // pad lanes re-load last entry
    const int ch = f & 3;
    const int r  = e / HW_;
    const int cl = e - r * HW_;
    int gh = by * TH - PD + r;
    gh = gh < 0 ? 0 : (gh > HT - 1 ? HT - 1 : gh);
    int gw = bx * TW - PD + cl;
    gw = gw < 0 ? 0 : (gw > WD - 1 ? WD - 1 : gw);
    off[q] = ch * PLANE + gh * WD + gw;  // clamped; OOB w[k] zeroed later
  }
}

__device__ __forceinline__ void issue_chunks(const float* gbase, const int* off,
                                             float* lds, int tid) {
#if __has_builtin(__builtin_amdgcn_global_load_lds)
#pragma unroll
  for (int q = 0; q < HCHUNK; ++q) {
    __builtin_amdgcn_global_load_lds(
        (const __attribute__((address_space(1))) void*)(gbase + off[q]),
        (__attribute__((address_space(3))) void*)(lds + q * 64), 4, 0, 0);
  }
#else
#pragma unroll
  for (int q = 0; q < HCHUNK; ++q) lds[q * 64 + tid] = gbase[off[q]];
  asm volatile("s_waitcnt lgkmcnt(0)" ::: "memory");
#endif
}

#define WAIT_VM(n_lit)                                      \
  asm volatile("s_waitcnt vmcnt(" #n_lit ")" ::: "memory"); \
  __builtin_amdgcn_sched_barrier(0)

// ------------------------- kernel 1: correlation ---------------------------
__global__ __launch_bounds__(64) void lnl2d_corr(const float* __restrict__ x,
                                                 float* __restrict__ wpart) {
  __shared__ float halo[3][HPADF];
  __shared__ float wstage[64 * WPAD];

  const int tid = (int)threadIdx.x;
  const int tx = tid & (TW - 1), ty = tid >> 4;
  const int bx = (int)blockIdx.x, by = (int)blockIdx.y;
  const int z = (int)blockIdx.z, n = z >> 2, chunk = z & 3;
  const int tile = (n * 20 + by) * 5 + bx;

  const float* xc = x + (size_t)n * CC * PLANE + (size_t)chunk * 32 * PLANE;

  int off[HCHUNK];
  make_off(off, bx, by, tid);

  float acc[K2];
#pragma unroll
  for (int k = 0; k < K2; ++k) acc[k] = 0.f;

  issue_chunks(xc, off, halo[0], tid);
  issue_chunks(xc + GSTRIDE, off, halo[1], tid);
  int goff = 2 * GSTRIDE;
#pragma unroll
  for (int g = 0; g < GPC; ++g) {
    if (g < GPC - 2) { issue_chunks(xc + goff, off, halo[(g + 2) % 3], tid); goff += GSTRIDE; }
    if (g < GPC - 2)      { WAIT_VM(28); }
    else if (g == GPC - 2){ WAIT_VM(14); }
    else                  { WAIT_VM(0); }
    const float* hb = halo[g % 3];
    const float4 c4 = *(const float4*)(hb + ((ty + PD) * HW_ + (tx + PD)) * 4);
#pragma unroll
    for (int di = 0; di < KK; ++di)
#pragma unroll
      for (int dj = 0; dj < KK; ++dj) {
        const float4 n4 = *(const float4*)(hb + ((ty + di) * HW_ + (tx + dj)) * 4);
        acc[di * KK + dj] += c4.x * n4.x + c4.y * n4.y + c4.z * n4.z + c4.w * n4.w;
      }
  }

  // zero OOB taps (matches zero-padding in the reference)
  const int h = by * TH + ty, w = bx * TW + tx;
#pragma unroll
  for (int di = 0; di < KK; ++di)
#pragma unroll
    for (int dj = 0; dj < KK; ++dj) {
      const int hh = h + di - PD, ww = w + dj - PD;
      if ((unsigned)hh >= (unsigned)HT || (unsigned)ww >= (unsigned)WD)
        acc[di * KK + dj] = 0.f;
    }

  // transpose via LDS -> 13 fully-coalesced float4 stores per block
#pragma unroll
  for (int k = 0; k < K2; ++k) wstage[tid * WPAD + k] = acc[k];
#pragma unroll
  for (int k = K2; k < WPAD; ++k) wstage[tid * WPAD + k] = 0.f;
  __syncthreads();
  float4* dst = (float4*)(wpart + ((size_t)(chunk * NTILES + tile) * 64) * WPAD);
  const float4* src = (const float4*)wstage;
#pragma unroll
  for (int i = 0; i < (64 * WPAD) / 4 / 64; ++i)  // 13
    dst[i * 64 + tid] = src[i * 64 + tid];
}

// ------------------- kernel 2: normalize + aggregate -----------------------
__global__ __launch_bounds__(64) void lnl2d_agg(const float* __restrict__ feat,
                                                const float* __restrict__ wpart,
                                                float* __restrict__ dout) {
  __shared__ float halo[3][HPADF];
  __shared__ float wstage[64 * WPAD];

  const int tid = (int)threadIdx.x;
  const int tx = tid & (TW - 1), ty = tid >> 4;
  const int bx = (int)blockIdx.x, by = (int)blockIdx.y;
  const int z = (int)blockIdx.z, n = z >> 2, chunk = z & 3;
  const int tile = (n * 20 + by) * 5 + bx;
  const int h = by * TH + ty, w = bx * TW + tx;

  const float* fc = feat + (size_t)n * CC * PLANE + (size_t)chunk * 32 * PLANE;
  float* out = dout;
  float* pw  = dout + OUT_ELEMS;

  int off[HCHUNK];
  make_off(off, bx, by, tid);

  // ---- sum the 4 chunk partials for this pixel, normalize ----
  float4 wv[WPAD / 4];
#pragma unroll
  for (int i = 0; i < WPAD / 4; ++i) wv[i] = make_float4(0.f, 0.f, 0.f, 0.f);
#pragma unroll
  for (int c = 0; c < CHUNKS; ++c) {
    const float4* p =
        (const float4*)(wpart + ((size_t)(c * NTILES + tile) * 64 + tid) * WPAD);
#pragma unroll
    for (int i = 0; i < WPAD / 4; ++i) {
      const float4 v = p[i];
      wv[i].x += v.x; wv[i].y += v.y; wv[i].z += v.z; wv[i].w += v.w;
    }
  }
  float wk[K2];
#pragma unroll
  for (int k = 0; k < K2; ++k) wk[k] = ((const float*)wv)[k];
  float ssum = 0.f;
#pragma unroll
  for (int k = 0; k < K2; ++k) ssum += wk[k];
  const float invs = 1.0f / ssum;
#pragma unroll
  for (int k = 0; k < K2; ++k) wk[k] *= invs;

  // drain so the counted-vmcnt staging pipeline starts clean
  WAIT_VM(0);

  // ---- phase 2: out[c] = sum_k wk * feat_neighbor (no stores in loop) ----
  float4 ov[GPC];
#pragma unroll
  for (int g = 0; g < GPC; ++g) ov[g] = make_float4(0.f, 0.f, 0.f, 0.f);

  issue_chunks(fc, off, halo[0], tid);
  issue_chunks(fc + GSTRIDE, off, halo[1], tid);
  int goff = 2 * GSTRIDE;
#pragma unroll
  for (int g = 0; g < GPC; ++g) {
    if (g < GPC - 2) { issue_chunks(fc + goff, off, halo[(g + 2) % 3], tid); goff += GSTRIDE; }
    if (g < GPC - 2)      { WAIT_VM(28); }
    else if (g == GPC - 2){ WAIT_VM(14); }
    else                  { WAIT_VM(0); }
    const float* hb = halo[g % 3];
#pragma unroll
    for (int di = 0; di < KK; ++di)
#pragma unroll
      for (int dj = 0; dj < KK; ++dj) {
        const float4 n4 = *(const float4*)(hb + ((ty + di) * HW_ + (tx + dj)) * 4);
        const float f = wk[di * KK + dj];
        ov[g].x += f * n4.x; ov[g].y += f * n4.y; ov[g].z += f * n4.z; ov[g].w += f * n4.w;
      }
  }

  const size_t ob = (size_t)n * CC * PLANE + (size_t)chunk * 32 * PLANE +
                    (size_t)(h * WD + w);
#pragma unroll
  for (int g = 0; g < GPC; ++g) {
    out[ob + (size_t)(4 * g + 0) * PLANE] = ov[g].x;
    out[ob + (size_t)(4 * g + 1) * PLANE] = ov[g].y;
    out[ob + (size_t)(4 * g + 2) * PLANE] = ov[g].z;
    out[ob + (size_t)(4 * g + 3) * PLANE] = ov[g].w;
  }

  // ---- pairwise_weight (chunk 0 only), via LDS transpose ----
  if (chunk == 0) {
#pragma unroll
    for (int k = 0; k < K2; ++k) wstage[tid * K2 + k] = wk[k];
    __syncthreads();
#pragma unroll
    for (int r = 0; r < TH; ++r) {
      float* dst = pw + (size_t)(n * PLANE + (by * TH + r) * WD + bx * TW) * K2;
      const float* src = wstage + r * TW * K2;
#pragma unroll
      for (int c2 = 0; c2 < (TW * K2) / 64; ++c2)
        dst[c2 * 64 + tid] = src[c2 * 64 + tid];
      if (tid < (TW * K2) - 64 * ((TW * K2) / 64))
        dst[64 * ((TW * K2) / 64) + tid] = src[64 * ((TW * K2) / 64) + tid];
    }
  }
}

// --------------- fallback: v1 fused single kernel (ws too small) -----------
__global__ __launch_bounds__(64) void lnl2d_fused(const float* __restrict__ x,
                                                  const float* __restrict__ feat,
                                                  float* __restrict__ dout) {
  __shared__ float halo[2][HPADF];
  __shared__ float wstage[TH * TW * K2];

  const int tid = (int)threadIdx.x;
  const int tx = tid & (TW - 1), ty = tid >> 4;
  const int bx = (int)blockIdx.x, by = (int)blockIdx.y, n = (int)blockIdx.z;
  const int h = by * TH + ty, w = bx * TW + tx;

  const float* xn = x + (size_t)n * CC * PLANE;
  const float* fn = feat + (size_t)n * CC * PLANE;
  float* out = dout;
  float* pw  = dout + OUT_ELEMS;

  int off[HCHUNK];
  make_off(off, bx, by, tid);

  float acc[K2];
#pragma unroll
  for (int k = 0; k < K2; ++k) acc[k] = 0.f;

  auto p1 = [&](const float* hb) {
    const float4 c4 = *(const float4*)(hb + ((ty + PD) * HW_ + (tx + PD)) * 4);
#pragma unroll
    for (int di = 0; di < KK; ++di)
#pragma unroll
      for (int dj = 0; dj < KK; ++dj) {
        const float4 n4 = *(const float4*)(hb + ((ty + di) * HW_ + (tx + dj)) * 4);
        acc[di * KK + dj] += c4.x * n4.x + c4.y * n4.y + c4.z * n4.z + c4.w * n4.w;
      }
  };

  issue_chunks(xn, off, halo[0], tid);
  int goff = GSTRIDE;
  for (int g = 0; g < 31; ++g) {
    issue_chunks(xn + goff, off, halo[(g + 1) & 1], tid);
    goff += GSTRIDE;
    WAIT_VM(14);
    p1(halo[g & 1]);
  }
  issue_chunks(fn, off, halo[0], tid);
  WAIT_VM(14);
  p1(halo[1]);

#pragma unroll
  for (int di = 0; di < KK; ++di)
#pragma unroll
    for (int dj = 0; dj < KK; ++dj) {
      const int hh = h + di - PD, ww = w + dj - PD;
      if ((unsigned)hh >= (unsigned)HT || (unsigned)ww >= (unsigned)WD)
        acc[di * KK + dj] = 0.f;
    }
  float ssum = 0.f;
#pragma unroll
  for (int k = 0; k < K2; ++k) ssum += acc[k];
  const float invs = 1.0f / ssum;
#pragma unroll
  for (int k = 0; k < K2; ++k) acc[k] *= invs;

#pragma unroll
  for (int k = 0; k < K2; ++k) wstage[tid * K2 + k] = acc[k];
  __syncthreads();
#pragma unroll
  for (int r = 0; r < TH; ++r) {
    float* dst = pw + (size_t)(n * PLANE + (by * TH + r) * WD + bx * TW) * K2;
    const float* src = wstage + r * TW * K2;
#pragma unroll
    for (int c2 = 0; c2 < (TW * K2) / 64; ++c2)
      dst[c2 * 64 + tid] = src[c2 * 64 + tid];
    if (tid < (TW * K2) - 64 * ((TW * K2) / 64))
      dst[64 * ((TW * K2) / 64) + tid] = src[64 * ((TW * K2) / 64) + tid];
  }

  const size_t obase = (size_t)n * CC * PLANE + (size_t)(h * WD + w);
  auto p2 = [&](const float* hb, int g) {
    float4 a = make_float4(0.f, 0.f, 0.f, 0.f);
#pragma unroll
    for (int di = 0; di < KK; ++di)
#pragma unroll
      for (int dj = 0; dj < KK; ++dj) {
        const float4 n4 = *(const float4*)(hb + ((ty + di) * HW_ + (tx + dj)) * 4);
        const float f = acc[di * KK + dj];
        a.x += f * n4.x; a.y += f * n4.y; a.z += f * n4.z; a.w += f * n4.w;
      }
    out[obase + (size_t)(4 * g + 0) * PLANE] = a.x;
    out[obase + (size_t)(4 * g + 1) * PLANE] = a.y;
    out[obase + (size_t)(4 * g + 2) * PLANE] = a.z;
    out[obase + (size_t)(4 * g + 3) * PLANE] = a.w;
  };

  goff = GSTRIDE;
  for (int g = 0; g < 31; ++g) {
    issue_chunks(fn + goff, off, halo[(g + 1) & 1], tid);
    goff += GSTRIDE;
    WAIT_VM(14);
    p2(halo[g & 1], g);
  }
  WAIT_VM(0);
  p2(halo[1], 31);
}

}  // namespace

extern "C" void kernel_launch(void* const* d_in, const int* in_sizes, int n_in,
                              void* d_out, int out_size, void* d_ws, size_t ws_size,
                              hipStream_t stream) {
  const float* x    = (const float*)d_in[0];
  const float* feat = (const float*)d_in[1];
  float* out        = (float*)d_out;

  if (ws_size >= WS_NEED) {
    float* wpart = (float*)d_ws;
    dim3 grid(5, 20, CN * CHUNKS);  // 1600 blocks each
    lnl2d_corr<<<grid, 64, 0, stream>>>(x, wpart);
    lnl2d_agg<<<grid, 64, 0, stream>>>(feat, wpart, out);
  } else {
    dim3 grid(5, 20, CN);  // 400 blocks fallback
    lnl2d_fused<<<grid, 64, 0, stream>>>(x, feat, out);
  }
}

// Round 4
// 137.891 us; speedup vs baseline: 1.2339x; 1.0362x over previous
//
#include <hip/hip_runtime.h>

// LocalNonLocal2D v3: single fused kernel, 4 waves/block.
//   wave w owns channels [32w, 32w+32): 8 groups of 4ch, each staged as a
//   22x10 channel-interleaved float4 halo tile via global_load_lds,
//   triple-buffered, 2-deep prefetch with counted s_waitcnt vmcnt(28).
//   Cross-wave w[49] reduction via LDS ds_add_f32 into wred[64][53]
//   (stride 53 -> conflict-free). Two __syncthreads total; both occur at
//   points where vmcnt==0, so implicit barrier drains don't stall loads.
// No workspace needed.

namespace {

constexpr int CN = 4, CC = 128, HT = 80, WD = 80;
constexpr int KK = 7, K2 = 49, PD = 3;
constexpr int TW = 16, TH = 4;            // pixel tile (64 px, lane = pixel)
constexpr int HW_ = TW + 6;               // 22 halo cols
constexpr int HH_ = TH + 6;               // 10 halo rows
constexpr int HENT = HW_ * HH_;           // 220 float4 halo entries
constexpr int HCHUNK = (HENT * 4 + 63) / 64;  // 14 chunks of 64 floats
constexpr int HPADF = HCHUNK * 64;        // 896 floats per halo buffer
constexpr int PLANE = HT * WD;            // 6400
constexpr int GSTRIDE = 4 * PLANE;        // one 4-channel group step
constexpr int OUT_ELEMS = CN * CC * PLANE;
constexpr int NW = 4;                     // waves per block
constexpr int GPW = 8;                    // 8 groups x 4ch = 32 ch per wave
constexpr int WR = 53;                    // wred row stride (odd -> 2-way max)

__device__ __forceinline__ void make_off(int* off, int bx, int by, int lane) {
#pragma unroll
  for (int q = 0; q < HCHUNK; ++q) {
    int f = q * 64 + lane;
    int e = f >> 2;
    if (e > HENT - 1) e = HENT - 1;  // pad lanes re-load last entry
    const int ch = f & 3;
    const int r  = e / HW_;
    const int cl = e - r * HW_;
    int gh = by * TH - PD + r;
    gh = gh < 0 ? 0 : (gh > HT - 1 ? HT - 1 : gh);
    int gw = bx * TW - PD + cl;
    gw = gw < 0 ? 0 : (gw > WD - 1 ? WD - 1 : gw);
    off[q] = ch * PLANE + gh * WD + gw;  // clamped; OOB taps zeroed later
  }
}

__device__ __forceinline__ void issue_chunks(const float* gbase, const int* off,
                                             float* lds) {
#if __has_builtin(__builtin_amdgcn_global_load_lds)
#pragma unroll
  for (int q = 0; q < HCHUNK; ++q) {
    __builtin_amdgcn_global_load_lds(
        (const __attribute__((address_space(1))) void*)(gbase + off[q]),
        (__attribute__((address_space(3))) void*)(lds + q * 64), 4, 0, 0);
  }
#else
  const int lane = (int)(threadIdx.x & 63);
#pragma unroll
  for (int q = 0; q < HCHUNK; ++q) lds[q * 64 + lane] = gbase[off[q]];
  asm volatile("s_waitcnt lgkmcnt(0)" ::: "memory");
#endif
}

#define WAIT_VM(n_lit)                                      \
  asm volatile("s_waitcnt vmcnt(" #n_lit ")" ::: "memory"); \
  __builtin_amdgcn_sched_barrier(0)

__global__ __launch_bounds__(256) void lnl2d_fused4(
    const float* __restrict__ x, const float* __restrict__ feat,
    float* __restrict__ dout) {
  __shared__ float halo[NW * 3][HPADF];   // 43008 B
  __shared__ float wred[64][WR];          // 13568 B
  __shared__ float inv[64];               // 256 B

  const int tid  = (int)threadIdx.x;
  const int wv   = tid >> 6;
  const int lane = tid & 63;
  const int tx = lane & (TW - 1), ty = lane >> 4;
  const int bx = (int)blockIdx.x, by = (int)blockIdx.y, n = (int)blockIdx.z;
  const int h = by * TH + ty, w = bx * TW + tx;

  const float* xw = x + (size_t)n * CC * PLANE + (size_t)wv * 32 * PLANE;
  const float* fw = feat + (size_t)n * CC * PLANE + (size_t)wv * 32 * PLANE;
  float* out = dout;
  float* pw  = dout + OUT_ELEMS;

  int off[HCHUNK];
  make_off(off, bx, by, lane);

  // init wred (all 256 threads); barrier happens before any atomics land
#pragma unroll
  for (int i = 0; i < (64 * WR + 255) / 256; ++i) {
    const int idx = i * 256 + tid;
    if (idx < 64 * WR) ((float*)wred)[idx] = 0.f;
  }
  __syncthreads();  // vmcnt==0 here: implicit drain is free

  // ---------------- phase 1: per-wave partial correlation ------------------
  float acc[K2];
#pragma unroll
  for (int k = 0; k < K2; ++k) acc[k] = 0.f;

  float* hb0 = halo[wv * 3 + 0];
  float* hb1 = halo[wv * 3 + 1];
  float* hb2 = halo[wv * 3 + 2];

  issue_chunks(xw, off, hb0);
  issue_chunks(xw + GSTRIDE, off, hb1);
  int goff = 2 * GSTRIDE;
#pragma unroll
  for (int g = 0; g < GPW; ++g) {
    if (g < GPW - 2) {
      float* dst = (g % 3 == 0) ? hb2 : ((g % 3 == 1) ? hb0 : hb1);  // (g+2)%3
      issue_chunks(xw + goff, off, dst);
      goff += GSTRIDE;
    }
    if (g < GPW - 2)      { WAIT_VM(28); }
    else if (g == GPW - 2){ WAIT_VM(14); }
    else                  { WAIT_VM(0); }
    const float* hb = (g % 3 == 0) ? hb0 : ((g % 3 == 1) ? hb1 : hb2);
    const float4 c4 = *(const float4*)(hb + ((ty + PD) * HW_ + (tx + PD)) * 4);
#pragma unroll
    for (int di = 0; di < KK; ++di)
#pragma unroll
      for (int dj = 0; dj < KK; ++dj) {
        const float4 n4 = *(const float4*)(hb + ((ty + di) * HW_ + (tx + dj)) * 4);
        acc[di * KK + dj] += c4.x * n4.x + c4.y * n4.y + c4.z * n4.z + c4.w * n4.w;
      }
  }

  // zero OOB taps (zero-padding semantics), then cross-wave reduce in LDS
#pragma unroll
  for (int di = 0; di < KK; ++di)
#pragma unroll
    for (int dj = 0; dj < KK; ++dj) {
      const int hh = h + di - PD, ww = w + dj - PD;
      if ((unsigned)hh >= (unsigned)HT || (unsigned)ww >= (unsigned)WD)
        acc[di * KK + dj] = 0.f;
    }
#pragma unroll
  for (int k = 0; k < K2; ++k) atomicAdd(&wred[lane][k], acc[k]);

  __syncthreads();  // vmcnt==0 (phase-1 drained to 0): free barrier

  // ---------------- normalize (overlaps feat prologue latency) -------------
  issue_chunks(fw, off, hb0);
  issue_chunks(fw + GSTRIDE, off, hb1);

  float wk[K2];
  float ssum = 0.f;
#pragma unroll
  for (int k = 0; k < K2; ++k) { wk[k] = wred[lane][k]; ssum += wk[k]; }
  const float invs = 1.0f / ssum;
#pragma unroll
  for (int k = 0; k < K2; ++k) wk[k] *= invs;
  if (wv == 0) inv[lane] = invs;  // for the pairwise store pass

  // ---------------- phase 2: per-wave aggregation over feat ----------------
  float4 ov[GPW];
#pragma unroll
  for (int g = 0; g < GPW; ++g) ov[g] = make_float4(0.f, 0.f, 0.f, 0.f);

  goff = 2 * GSTRIDE;
#pragma unroll
  for (int g = 0; g < GPW; ++g) {
    if (g < GPW - 2) {
      float* dst = (g % 3 == 0) ? hb2 : ((g % 3 == 1) ? hb0 : hb1);
      issue_chunks(fw + goff, off, dst);
      goff += GSTRIDE;
    }
    if (g < GPW - 2)      { WAIT_VM(28); }
    else if (g == GPW - 2){ WAIT_VM(14); }
    else                  { WAIT_VM(0); }
    const float* hb = (g % 3 == 0) ? hb0 : ((g % 3 == 1) ? hb1 : hb2);
#pragma unroll
    for (int di = 0; di < KK; ++di)
#pragma unroll
      for (int dj = 0; dj < KK; ++dj) {
        const float4 n4 = *(const float4*)(hb + ((ty + di) * HW_ + (tx + dj)) * 4);
        const float f = wk[di * KK + dj];
        ov[g].x += f * n4.x; ov[g].y += f * n4.y; ov[g].z += f * n4.z; ov[g].w += f * n4.w;
      }
  }

  const size_t ob = (size_t)n * CC * PLANE + (size_t)wv * 32 * PLANE +
                    (size_t)(h * WD + w);
#pragma unroll
  for (int g = 0; g < GPW; ++g) {
    out[ob + (size_t)(4 * g + 0) * PLANE] = ov[g].x;
    out[ob + (size_t)(4 * g + 1) * PLANE] = ov[g].y;
    out[ob + (size_t)(4 * g + 2) * PLANE] = ov[g].z;
    out[ob + (size_t)(4 * g + 3) * PLANE] = ov[g].w;
  }

  __syncthreads();  // orders inv[] + wred for the cooperative pairwise store

  // ---- pairwise_weight: (n,h,w,k) layout; per tile row 784 contiguous ----
#pragma unroll
  for (int r = 0; r < TH; ++r) {
    float* seg = pw + (size_t)(n * PLANE + (by * TH + r) * WD + bx * TW) * K2;
#pragma unroll
    for (int i = 0; i < (TW * K2) / 256; ++i) {  // 3 full chunks of 256
      const int idx = i * 256 + tid;
      const int col = idx / K2, k = idx - col * K2;
      seg[idx] = wred[r * TW + col][k] * inv[r * TW + col];
    }
    const int rem = TW * K2 - 256 * ((TW * K2) / 256);  // 16
    if (tid < rem) {
      const int idx = 256 * ((TW * K2) / 256) + tid;
      const int col = idx / K2, k = idx - col * K2;
      seg[idx] = wred[r * TW + col][k] * inv[r * TW + col];
    }
  }
}

}  // namespace

extern "C" void kernel_launch(void* const* d_in, const int* in_sizes, int n_in,
                              void* d_out, int out_size, void* d_ws, size_t ws_size,
                              hipStream_t stream) {
  const float* x    = (const float*)d_in[0];
  const float* feat = (const float*)d_in[1];
  float* out        = (float*)d_out;
  dim3 grid(WD / TW, HT / TH, CN);  // (5, 20, 4) = 400 blocks x 256 threads
  lnl2d_fused4<<<grid, 256, 0, stream>>>(x, feat, out);
}